// Round 14
// baseline (225.145 us; speedup 1.0000x reference)
//
#include <hip/hip_runtime.h>
#include <hip/hip_bf16.h>
#include <stdint.h>

#define T_TOK 4096
#define DH 1024
#define DI 1408
#define NE 8
#define TOPK 2
#define PADROWS 9216   // 8192 assignments + up to 8*127 pad (128-row tiles)

typedef short s16x8 __attribute__((ext_vector_type(8)));
typedef float f32x4 __attribute__((ext_vector_type(4)));
typedef float f32x4v __attribute__((ext_vector_type(4)));
typedef unsigned u32x4v __attribute__((ext_vector_type(4)));

__device__ inline unsigned f2bf(float f) {
    __hip_bfloat16 h = __float2bfloat16(f);
    return (unsigned)*(unsigned short*)&h;
}

#define GLDS(src, dst) __builtin_amdgcn_global_load_lds( \
    (const __attribute__((address_space(1))) void*)(src), \
    (__attribute__((address_space(3))) void*)(dst), 16, 0, 0)

#define SBAR()  __builtin_amdgcn_s_barrier()
#define SCHED() __builtin_amdgcn_sched_barrier(0)

// ---------------- fp32 -> bf16 convert, 3 tensors interleaved, nontemporal ----------------
__global__ __launch_bounds__(256) void cvt3_kernel(const float* __restrict__ s0,
        const float* __restrict__ s1, const float* __restrict__ s2,
        unsigned* __restrict__ t0, unsigned* __restrict__ t1,
        unsigned* __restrict__ t2, int n8) {
    int i = blockIdx.x * blockDim.x + threadIdx.x;
    int stride = gridDim.x * blockDim.x;
    const f32x4v* f0 = (const f32x4v*)s0;
    const f32x4v* f1 = (const f32x4v*)s1;
    const f32x4v* f2 = (const f32x4v*)s2;
    for (; i < n8; i += stride) {
        f32x4v a0 = __builtin_nontemporal_load(&f0[2 * i]);
        f32x4v b0 = __builtin_nontemporal_load(&f0[2 * i + 1]);
        f32x4v a1 = __builtin_nontemporal_load(&f1[2 * i]);
        f32x4v b1 = __builtin_nontemporal_load(&f1[2 * i + 1]);
        f32x4v a2 = __builtin_nontemporal_load(&f2[2 * i]);
        f32x4v b2 = __builtin_nontemporal_load(&f2[2 * i + 1]);
        u32x4v o0, o1, o2;
        o0.x = f2bf(a0.x) | (f2bf(a0.y) << 16); o0.y = f2bf(a0.z) | (f2bf(a0.w) << 16);
        o0.z = f2bf(b0.x) | (f2bf(b0.y) << 16); o0.w = f2bf(b0.z) | (f2bf(b0.w) << 16);
        o1.x = f2bf(a1.x) | (f2bf(a1.y) << 16); o1.y = f2bf(a1.z) | (f2bf(a1.w) << 16);
        o1.z = f2bf(b1.x) | (f2bf(b1.y) << 16); o1.w = f2bf(b1.z) | (f2bf(b1.w) << 16);
        o2.x = f2bf(a2.x) | (f2bf(a2.y) << 16); o2.y = f2bf(a2.z) | (f2bf(a2.w) << 16);
        o2.z = f2bf(b2.x) | (f2bf(b2.y) << 16); o2.w = f2bf(b2.z) | (f2bf(b2.w) << 16);
        __builtin_nontemporal_store(o0, (u32x4v*)&t0[4 * i]);
        __builtin_nontemporal_store(o1, (u32x4v*)&t1[4 * i]);
        __builtin_nontemporal_store(o2, (u32x4v*)&t2[4 * i]);
    }
}

// ---------------- router: logits, softmax, top-2, renorm; x->bf16. NO atomics ----------------
__global__ __launch_bounds__(256) void router_kernel(const float* __restrict__ x,
                              const float* __restrict__ gw,
                              float* __restrict__ logits_out,
                              int* __restrict__ tokE, float* __restrict__ tokW,
                              unsigned short* __restrict__ xb) {
    int wave = threadIdx.x >> 6;
    int lane = threadIdx.x & 63;
    int t = blockIdx.x * 4 + wave;
    const float4* xr = (const float4*)(x + (size_t)t * DH);

    float acc[NE];
#pragma unroll
    for (int e = 0; e < NE; ++e) acc[e] = 0.f;

#pragma unroll
    for (int i = 0; i < 4; ++i) {
        float4 xv = xr[lane + i * 64];
#pragma unroll
        for (int e = 0; e < NE; ++e) {
            float4 g = ((const float4*)(gw + (size_t)e * DH))[lane + i * 64];
            acc[e] += xv.x * g.x + xv.y * g.y + xv.z * g.z + xv.w * g.w;
        }
        uint2 o;
        o.x = f2bf(xv.x) | (f2bf(xv.y) << 16);
        o.y = f2bf(xv.z) | (f2bf(xv.w) << 16);
        *(uint2*)(xb + (size_t)t * DH + (lane + i * 64) * 4) = o;
    }
#pragma unroll
    for (int e = 0; e < NE; ++e) {
#pragma unroll
        for (int off = 32; off > 0; off >>= 1) acc[e] += __shfl_xor(acc[e], off, 64);
    }
    if (lane == 0) {
        float mx = acc[0];
#pragma unroll
        for (int e = 1; e < NE; ++e) mx = fmaxf(mx, acc[e]);
        float p[NE]; float s = 0.f;
#pragma unroll
        for (int e = 0; e < NE; ++e) { p[e] = expf(acc[e] - mx); s += p[e]; }
        float inv = 1.f / s;
#pragma unroll
        for (int e = 0; e < NE; ++e) p[e] *= inv;
        int i0 = 0, i1 = -1; float p0 = -1.f, p1 = -1.f;
#pragma unroll
        for (int e = 0; e < NE; ++e) {
            float v = p[e];
            if (v > p0) { p1 = p0; i1 = i0; p0 = v; i0 = e; }
            else if (v > p1) { p1 = v; i1 = e; }
        }
        float wsum = p0 + p1;
#pragma unroll
        for (int e = 0; e < NE; ++e) logits_out[(size_t)t * NE + e] = acc[e];
        tokE[2 * t]     = i0;  tokE[2 * t + 1] = i1;
        tokW[2 * t]     = p0 / wsum;  tokW[2 * t + 1] = p1 / wsum;
    }
}

// ---------------- hist + prefix + scatter: ONE single-block kernel, LDS cursor ----------------
__global__ __launch_bounds__(1024) void histscatter_kernel(const int* __restrict__ tokE,
        const float* __restrict__ tokW,
        int* __restrict__ countsG, int* __restrict__ padOffG,
        int* __restrict__ assignTok, float* __restrict__ assignW) {
    __shared__ int wc[16][NE];
    __shared__ int padOff[NE + 1];
    __shared__ int cursor[NE];
    int tid = threadIdx.x, wave = tid >> 6, lane = tid & 63;

    int cnt[NE];
#pragma unroll
    for (int e = 0; e < NE; ++e) cnt[e] = 0;
    for (int i = tid; i < T_TOK * TOPK; i += 1024) {
        int v = tokE[i];
#pragma unroll
        for (int e = 0; e < NE; ++e)
            cnt[e] += (int)__popcll(__ballot(v == e));
    }
    // zero assignTok (pad entries -> token 0)
    for (int i = tid; i < PADROWS; i += 1024) assignTok[i] = 0;
    if (lane == 0) {
#pragma unroll
        for (int e = 0; e < NE; ++e) wc[wave][e] = cnt[e];
    }
    __syncthreads();
    if (tid == 0) {
        int r = 0;
        for (int e = 0; e < NE; ++e) {
            int c = 0;
            for (int w = 0; w < 16; ++w) c += wc[w][e];
            countsG[e] = c;
            padOff[e] = r;
            padOffG[e] = r;
            cursor[e] = 0;
            r += ((c + 127) >> 7) << 7;
        }
        padOff[NE] = r;
        padOffG[NE] = r;
    }
    __syncthreads();

    unsigned long long lmask = (1ull << lane) - 1ull;
    for (int i = tid; i < T_TOK * TOPK; i += 1024) {
        int e = tokE[i];
#pragma unroll
        for (int ex = 0; ex < NE; ++ex) {
            unsigned long long m = __ballot(e == ex);
            if (e == ex) {
                int rank = (int)__popcll(m & lmask);
                int leader = __ffsll((long long)m) - 1;
                int b = 0;
                if (rank == 0) b = atomicAdd(&cursor[ex], (int)__popcll(m));
                b = __shfl(b, leader, 64);
                int slot = padOff[ex] + b + rank;
                assignTok[slot] = i >> 1;
                assignW[slot] = tokW[i];
            }
        }
    }
}

// ---------------- grouped GEMM A: h = silu(xb[tok] Wg^T) * (xb[tok] Wu^T) ----------------
// 128x128 tile, 8 waves (64x32/wave), TRIPLE-buffer LDS, 2-deep counted-vmcnt pipeline.
__global__ __launch_bounds__(512) void gemmA_kernel(
        const unsigned short* __restrict__ xb,
        const unsigned short* __restrict__ gpb, const unsigned short* __restrict__ upb,
        const int* __restrict__ padOff, const int* __restrict__ assignTok,
        unsigned short* __restrict__ h) {
    int bid = blockIdx.x;
    int nid = (bid & 7) * 99 + (bid >> 3);          // 792 = 8 XCD * 99, bijective
    int colblk = nid / 72, rowblk = nid - colblk * 72;
    int pr0 = rowblk * 128;
    int n0 = colblk * 128;
    int e = -1;
#pragma unroll
    for (int i = 0; i < NE; ++i)
        if (pr0 >= padOff[i] && pr0 < padOff[i + 1]) e = i;
    if (e < 0) return;

    __shared__ unsigned short As[3][128 * 32];
    __shared__ unsigned short Bgs[3][128 * 32];
    __shared__ unsigned short Bus[3][128 * 32];

    int tid = threadIdx.x;
    int lane = tid & 63;
    int w = tid >> 6;
    int wm = (w >> 2) * 64;
    int wn = (w & 3) * 32;

    int srow = w * 16 + (lane >> 2);
    int aslot = (((lane & 3) ^ ((lane >> 3) & 3)) << 3);
    int tok = assignTok[pr0 + srow];
    const unsigned short* a0   = xb  + (size_t)tok * DH + aslot;
    const unsigned short* gsrc = gpb + ((size_t)e * DI + n0 + srow) * DH + aslot;
    const unsigned short* usrc = upb + ((size_t)e * DI + n0 + srow) * DH + aslot;
    int sdst = w * 512;

    int rq = (((lane >> 4) ^ ((lane >> 1) & 3)) << 3);

    f32x4 accG[4][2], accU[4][2];
#pragma unroll
    for (int i = 0; i < 4; ++i)
#pragma unroll
        for (int j = 0; j < 2; ++j) {
            accG[i][j] = (f32x4){0.f, 0.f, 0.f, 0.f};
            accU[i][j] = (f32x4){0.f, 0.f, 0.f, 0.f};
        }

#define STAGE_A(buf, k0) do { \
    GLDS(a0 + (k0),   &As[buf][sdst]); \
    GLDS(gsrc + (k0), &Bgs[buf][sdst]); \
    GLDS(usrc + (k0), &Bus[buf][sdst]); \
    } while (0)

#define KCOMP_A(cur, VMS) do { \
    asm volatile("s_waitcnt vmcnt(" VMS ")" ::: "memory"); \
    SBAR(); SCHED(); \
    s16x8 af[4], bgf[2], bu2[2]; \
    _Pragma("unroll") \
    for (int i = 0; i < 4; ++i) \
        af[i] = *(const s16x8*)&As[cur][(wm + 16 * i + (lane & 15)) * 32 + rq]; \
    _Pragma("unroll") \
    for (int j = 0; j < 2; ++j) { \
        bgf[j] = *(const s16x8*)&Bgs[cur][(wn + 16 * j + (lane & 15)) * 32 + rq]; \
        bu2[j] = *(const s16x8*)&Bus[cur][(wn + 16 * j + (lane & 15)) * 32 + rq]; \
    } \
    asm volatile("s_waitcnt lgkmcnt(0)" ::: "memory"); \
    SCHED(); \
    SBAR(); \
    SCHED(); \
    _Pragma("unroll") \
    for (int i = 0; i < 4; ++i) \
        _Pragma("unroll") \
        for (int j = 0; j < 2; ++j) { \
            accG[i][j] = __builtin_amdgcn_mfma_f32_16x16x32_bf16(af[i], bgf[j], accG[i][j], 0, 0, 0); \
            accU[i][j] = __builtin_amdgcn_mfma_f32_16x16x32_bf16(af[i], bu2[j], accU[i][j], 0, 0, 0); \
        } \
    } while (0)

    STAGE_A(0, 0);
    STAGE_A(1, 32);
    int bs = 2, bc = 0;
    for (int ks = 0; ks < 30; ++ks) {
        STAGE_A(bs, (ks + 2) * 32);
        KCOMP_A(bc, "6");
        bs = (bs == 2) ? 0 : bs + 1;
        bc = (bc == 2) ? 0 : bc + 1;
    }
    KCOMP_A(0, "3");   // ks = 30
    KCOMP_A(1, "0");   // ks = 31
#undef STAGE_A
#undef KCOMP_A

#pragma unroll
    for (int i = 0; i < 4; ++i) {
        int rowb = pr0 + wm + 16 * i + ((lane >> 4) << 2);
#pragma unroll
        for (int j = 0; j < 2; ++j) {
            int col = n0 + wn + 16 * j + (lane & 15);
#pragma unroll
            for (int r = 0; r < 4; ++r) {
                float g = accG[i][j][r], u = accU[i][j][r];
                float val = (g / (1.f + __expf(-g))) * u;
                h[(size_t)(rowb + r) * DI + col] = (unsigned short)f2bf(val);
            }
        }
    }
}

// ---------------- grouped GEMM B: out[tok] += w * (h Wd^T), atomic epilogue ----------------
// 128x128 tile, 4 waves of 64x64, TRIPLE-buffer LDS, 2-deep counted-vmcnt pipeline.
__global__ __launch_bounds__(256) void gemmB_kernel(
        const unsigned short* __restrict__ h,
        const unsigned short* __restrict__ dpb,
        const int* __restrict__ padOff, const int* __restrict__ counts,
        const int* __restrict__ assignTok, const float* __restrict__ assignW,
        float* __restrict__ out) {
    int bid = blockIdx.x;
    int nid = (bid & 7) * 72 + (bid >> 3);          // 576 = 8 XCD * 72, bijective
    int colblk = nid / 72, rowblk = nid - colblk * 72;
    int pr0 = rowblk * 128;
    int n0 = colblk * 128;
    int e = -1, base = 0;
#pragma unroll
    for (int i = 0; i < NE; ++i)
        if (pr0 >= padOff[i] && pr0 < padOff[i + 1]) { e = i; base = padOff[i]; }
    if (e < 0) return;
    int cnt = counts[e];

    __shared__ unsigned short As[3][128 * 32];
    __shared__ unsigned short Bs[3][128 * 32];

    int tid = threadIdx.x;
    int lane = tid & 63;
    int w = tid >> 6;
    int wm = (w >> 1) * 64;
    int wn = (w & 1) * 64;

    int srow = w * 32 + (lane >> 2);
    int aslot = (((lane & 3) ^ ((lane >> 3) & 3)) << 3);
    const unsigned short* a0   = h   + (size_t)(pr0 + srow) * DI + aslot;
    const unsigned short* a1   = h   + (size_t)(pr0 + srow + 16) * DI + aslot;
    const unsigned short* b0   = dpb + ((size_t)e * DH + n0 + srow) * DI + aslot;
    const unsigned short* b1   = dpb + ((size_t)e * DH + n0 + srow + 16) * DI + aslot;
    int sdst = w * 1024;

    int rq = (((lane >> 4) ^ ((lane >> 1) & 3)) << 3);

    f32x4 acc[4][4];
#pragma unroll
    for (int i = 0; i < 4; ++i)
#pragma unroll
        for (int j = 0; j < 4; ++j) acc[i][j] = (f32x4){0.f, 0.f, 0.f, 0.f};

#define STAGE_B(buf, k0) do { \
    GLDS(a0 + (k0), &As[buf][sdst]); \
    GLDS(a1 + (k0), &As[buf][sdst + 512]); \
    GLDS(b0 + (k0), &Bs[buf][sdst]); \
    GLDS(b1 + (k0), &Bs[buf][sdst + 512]); \
    } while (0)

#define KCOMP_B(cur, VMS) do { \
    asm volatile("s_waitcnt vmcnt(" VMS ")" ::: "memory"); \
    SBAR(); SCHED(); \
    s16x8 af[4], bf[4]; \
    _Pragma("unroll") \
    for (int i = 0; i < 4; ++i) \
        af[i] = *(const s16x8*)&As[cur][(wm + 16 * i + (lane & 15)) * 32 + rq]; \
    _Pragma("unroll") \
    for (int j = 0; j < 4; ++j) \
        bf[j] = *(const s16x8*)&Bs[cur][(wn + 16 * j + (lane & 15)) * 32 + rq]; \
    asm volatile("s_waitcnt lgkmcnt(0)" ::: "memory"); \
    SCHED(); \
    SBAR(); \
    SCHED(); \
    _Pragma("unroll") \
    for (int i = 0; i < 4; ++i) \
        _Pragma("unroll") \
        for (int j = 0; j < 4; ++j) \
            acc[i][j] = __builtin_amdgcn_mfma_f32_16x16x32_bf16(af[i], bf[j], acc[i][j], 0, 0, 0); \
    } while (0)

    STAGE_B(0, 0);
    STAGE_B(1, 32);
    int bs = 2, bc = 0;
    for (int ks = 0; ks < 42; ++ks) {
        STAGE_B(bs, (ks + 2) * 32);
        KCOMP_B(bc, "8");
        bs = (bs == 2) ? 0 : bs + 1;
        bc = (bc == 2) ? 0 : bc + 1;
    }
    KCOMP_B(0, "4");   // ks = 42
    KCOMP_B(1, "0");   // ks = 43
#undef STAGE_B
#undef KCOMP_B

#pragma unroll
    for (int i = 0; i < 4; ++i) {
        int rowb = pr0 + wm + 16 * i + ((lane >> 4) << 2);
#pragma unroll
        for (int r = 0; r < 4; ++r) {
            int prow = rowb + r;
            if (prow - base < cnt) {
                int tok = assignTok[prow];
                float wgt = assignW[prow];
                float* orow = out + (size_t)tok * DH;
#pragma unroll
                for (int j = 0; j < 4; ++j) {
                    int col = n0 + wn + 16 * j + (lane & 15);
                    atomicAdd(&orow[col], wgt * acc[i][j][r]);
                }
            }
        }
    }
}

extern "C" void kernel_launch(void* const* d_in, const int* in_sizes, int n_in,
                              void* d_out, int out_size, void* d_ws, size_t ws_size,
                              hipStream_t stream) {
    const float* x  = (const float*)d_in[0];
    const float* gw = (const float*)d_in[1];
    const float* gp = (const float*)d_in[2];
    const float* up = (const float*)d_in[3];
    const float* dp = (const float*)d_in[4];
    float* out = (float*)d_out;
    float* logits = out + (size_t)T_TOK * DH;

    char* ws = (char*)d_ws;
    int*   counts    = (int*)(ws + 0);
    int*   padOff    = (int*)(ws + 128);
    int*   tokE      = (int*)(ws + 4096);                       // 32 KB
    float* tokW      = (float*)(ws + 36864);                    // 32 KB
    float* assignW   = (float*)(ws + 69632);                    // 36 KB
    int*   assignTok = (int*)(ws + 106496);                     // 36 KB
    unsigned short* xb   = (unsigned short*)(ws + 147456);      // 8.39 MB
    unsigned short* gpb  = (unsigned short*)(ws + 8536064);     // 23.07 MB
    unsigned short* upb  = (unsigned short*)(ws + 31604736);    // 23.07 MB
    unsigned short* dpb  = (unsigned short*)(ws + 54673408);    // 23.07 MB
    unsigned short* h    = (unsigned short*)(ws + 77742080);    // 25.95 MB

    // out must start at zero every call (atomic accumulate, exactly 2 adds/elem)
    hipMemsetAsync(d_out, 0, (size_t)T_TOK * DH * sizeof(float), stream);

    const int NW8 = NE * DI * DH / 8;   // 1441792
    cvt3_kernel<<<2048, 256, 0, stream>>>(gp, up, dp,
                                          (unsigned*)gpb, (unsigned*)upb, (unsigned*)dpb, NW8);

    router_kernel<<<T_TOK / 4, 256, 0, stream>>>(x, gw, logits, tokE, tokW, xb);
    histscatter_kernel<<<1, 1024, 0, stream>>>(tokE, tokW, counts, padOff, assignTok, assignW);

    gemmA_kernel<<<dim3((DI / 128) * (PADROWS / 128)), 512, 0, stream>>>(xb, gpb, upb, padOff, assignTok, h);
    gemmB_kernel<<<(DH / 128) * (PADROWS / 128), 256, 0, stream>>>(h, dpb, padOff, counts, assignTok, assignW, out);
}

// Round 15
// 184.906 us; speedup vs baseline: 1.2176x; 1.2176x over previous
//
#include <hip/hip_runtime.h>
#include <hip/hip_bf16.h>
#include <stdint.h>

#define T_TOK 4096
#define DH 1024
#define DI 1408
#define NE 8
#define TOPK 2
#define PADROWS 9216   // 8192 assignments + up to 8*127 pad (128-row tiles)

typedef short s16x8 __attribute__((ext_vector_type(8)));
typedef float f32x4 __attribute__((ext_vector_type(4)));

__device__ inline unsigned f2bf(float f) {
    __hip_bfloat16 h = __float2bfloat16(f);
    return (unsigned)*(unsigned short*)&h;
}
__device__ inline float bf2f(unsigned short u) {
    return __uint_as_float(((unsigned)u) << 16);
}

#define GLDS(src, dst) __builtin_amdgcn_global_load_lds( \
    (const __attribute__((address_space(1))) void*)(src), \
    (__attribute__((address_space(3))) void*)(dst), 16, 0, 0)

#define SBAR()  __builtin_amdgcn_s_barrier()
#define SCHED() __builtin_amdgcn_sched_barrier(0)

// ---------------- fp32 -> bf16 convert, 3 tensors interleaved (ILP), 16B stores ----------------
__global__ __launch_bounds__(256) void cvt3_kernel(const float* __restrict__ s0,
        const float* __restrict__ s1, const float* __restrict__ s2,
        uint4* __restrict__ t0, uint4* __restrict__ t1, uint4* __restrict__ t2, int n8) {
    int i = blockIdx.x * blockDim.x + threadIdx.x;
    int stride = gridDim.x * blockDim.x;
    const float4* f0 = (const float4*)s0;
    const float4* f1 = (const float4*)s1;
    const float4* f2 = (const float4*)s2;
    for (; i < n8; i += stride) {
        float4 a0 = f0[2 * i], b0 = f0[2 * i + 1];
        float4 a1 = f1[2 * i], b1 = f1[2 * i + 1];
        float4 a2 = f2[2 * i], b2 = f2[2 * i + 1];
        uint4 o0, o1, o2;
        o0.x = f2bf(a0.x) | (f2bf(a0.y) << 16); o0.y = f2bf(a0.z) | (f2bf(a0.w) << 16);
        o0.z = f2bf(b0.x) | (f2bf(b0.y) << 16); o0.w = f2bf(b0.z) | (f2bf(b0.w) << 16);
        o1.x = f2bf(a1.x) | (f2bf(a1.y) << 16); o1.y = f2bf(a1.z) | (f2bf(a1.w) << 16);
        o1.z = f2bf(b1.x) | (f2bf(b1.y) << 16); o1.w = f2bf(b1.z) | (f2bf(b1.w) << 16);
        o2.x = f2bf(a2.x) | (f2bf(a2.y) << 16); o2.y = f2bf(a2.z) | (f2bf(a2.w) << 16);
        o2.z = f2bf(b2.x) | (f2bf(b2.y) << 16); o2.w = f2bf(b2.z) | (f2bf(b2.w) << 16);
        t0[i] = o0; t1[i] = o1; t2[i] = o2;
    }
}

// ---------------- router: logits, softmax, top-2, renorm; x->bf16. NO atomics ----------------
__global__ __launch_bounds__(256) void router_kernel(const float* __restrict__ x,
                              const float* __restrict__ gw,
                              float* __restrict__ logits_out,
                              int* __restrict__ tokE, float* __restrict__ tokW,
                              unsigned short* __restrict__ xb) {
    int wave = threadIdx.x >> 6;
    int lane = threadIdx.x & 63;
    int t = blockIdx.x * 4 + wave;
    const float4* xr = (const float4*)(x + (size_t)t * DH);

    float acc[NE];
#pragma unroll
    for (int e = 0; e < NE; ++e) acc[e] = 0.f;

#pragma unroll
    for (int i = 0; i < 4; ++i) {
        float4 xv = xr[lane + i * 64];
#pragma unroll
        for (int e = 0; e < NE; ++e) {
            float4 g = ((const float4*)(gw + (size_t)e * DH))[lane + i * 64];
            acc[e] += xv.x * g.x + xv.y * g.y + xv.z * g.z + xv.w * g.w;
        }
        uint2 o;
        o.x = f2bf(xv.x) | (f2bf(xv.y) << 16);
        o.y = f2bf(xv.z) | (f2bf(xv.w) << 16);
        *(uint2*)(xb + (size_t)t * DH + (lane + i * 64) * 4) = o;
    }
#pragma unroll
    for (int e = 0; e < NE; ++e) {
#pragma unroll
        for (int off = 32; off > 0; off >>= 1) acc[e] += __shfl_xor(acc[e], off, 64);
    }
    if (lane == 0) {
        float mx = acc[0];
#pragma unroll
        for (int e = 1; e < NE; ++e) mx = fmaxf(mx, acc[e]);
        float p[NE]; float s = 0.f;
#pragma unroll
        for (int e = 0; e < NE; ++e) { p[e] = expf(acc[e] - mx); s += p[e]; }
        float inv = 1.f / s;
#pragma unroll
        for (int e = 0; e < NE; ++e) p[e] *= inv;
        int i0 = 0, i1 = -1; float p0 = -1.f, p1 = -1.f;
#pragma unroll
        for (int e = 0; e < NE; ++e) {
            float v = p[e];
            if (v > p0) { p1 = p0; i1 = i0; p0 = v; i0 = e; }
            else if (v > p1) { p1 = v; i1 = e; }
        }
        float wsum = p0 + p1;
#pragma unroll
        for (int e = 0; e < NE; ++e) logits_out[(size_t)t * NE + e] = acc[e];
        tokE[2 * t]     = i0;  tokE[2 * t + 1] = i1;
        tokW[2 * t]     = p0 / wsum;  tokW[2 * t + 1] = p1 / wsum;
    }
}

// ---------------- hist + prefix + scatter: ONE single-block kernel, LDS cursor ----------------
__global__ __launch_bounds__(1024) void histscatter_kernel(const int* __restrict__ tokE,
        int* __restrict__ countsG, int* __restrict__ padOffG,
        int* __restrict__ assignTok, int* __restrict__ tokSlot) {
    __shared__ int wc[16][NE];
    __shared__ int padOff[NE + 1];
    __shared__ int cursor[NE];
    int tid = threadIdx.x, wave = tid >> 6, lane = tid & 63;

    int cnt[NE];
#pragma unroll
    for (int e = 0; e < NE; ++e) cnt[e] = 0;
    for (int i = tid; i < T_TOK * TOPK; i += 1024) {
        int v = tokE[i];
#pragma unroll
        for (int e = 0; e < NE; ++e)
            cnt[e] += (int)__popcll(__ballot(v == e));
    }
    // zero assignTok (pad entries -> token 0); replaces host-side memset
    for (int i = tid; i < PADROWS; i += 1024) assignTok[i] = 0;
    if (lane == 0) {
#pragma unroll
        for (int e = 0; e < NE; ++e) wc[wave][e] = cnt[e];
    }
    __syncthreads();
    if (tid == 0) {
        int r = 0;
        for (int e = 0; e < NE; ++e) {
            int c = 0;
            for (int w = 0; w < 16; ++w) c += wc[w][e];
            countsG[e] = c;
            padOff[e] = r;
            padOffG[e] = r;
            cursor[e] = 0;
            r += ((c + 127) >> 7) << 7;
        }
        padOff[NE] = r;
        padOffG[NE] = r;
    }
    __syncthreads();

    unsigned long long lmask = (1ull << lane) - 1ull;
    for (int i = tid; i < T_TOK * TOPK; i += 1024) {
        int e = tokE[i];
#pragma unroll
        for (int ex = 0; ex < NE; ++ex) {
            unsigned long long m = __ballot(e == ex);
            if (e == ex) {
                int rank = (int)__popcll(m & lmask);
                int leader = __ffsll((long long)m) - 1;
                int b = 0;
                if (rank == 0) b = atomicAdd(&cursor[ex], (int)__popcll(m));
                b = __shfl(b, leader, 64);
                int slot = padOff[ex] + b + rank;
                assignTok[slot] = i >> 1;
                tokSlot[i] = slot;
            }
        }
    }
}

// ---------------- grouped GEMM A: h = silu(xb[tok] Wg^T) * (xb[tok] Wu^T) ----------------
// 128x128 tile, 8 waves (64x32/wave), TRIPLE-buffer LDS, 2-deep counted-vmcnt pipeline.
__global__ __launch_bounds__(512) void gemmA_kernel(
        const unsigned short* __restrict__ xb,
        const unsigned short* __restrict__ gpb, const unsigned short* __restrict__ upb,
        const int* __restrict__ padOff, const int* __restrict__ assignTok,
        unsigned short* __restrict__ h) {
    int bid = blockIdx.x;
    int nid = (bid & 7) * 99 + (bid >> 3);          // 792 = 8 XCD * 99, bijective
    int colblk = nid / 72, rowblk = nid - colblk * 72;
    int pr0 = rowblk * 128;
    int n0 = colblk * 128;
    int e = -1;
#pragma unroll
    for (int i = 0; i < NE; ++i)
        if (pr0 >= padOff[i] && pr0 < padOff[i + 1]) e = i;
    if (e < 0) return;

    __shared__ unsigned short As[3][128 * 32];    // 8 KB each -> 72 KB total
    __shared__ unsigned short Bgs[3][128 * 32];
    __shared__ unsigned short Bus[3][128 * 32];

    int tid = threadIdx.x;
    int lane = tid & 63;
    int w = tid >> 6;
    int wm = (w >> 2) * 64;
    int wn = (w & 3) * 32;

    int srow = w * 16 + (lane >> 2);
    int aslot = (((lane & 3) ^ ((lane >> 3) & 3)) << 3);
    int tok = assignTok[pr0 + srow];
    const unsigned short* a0   = xb  + (size_t)tok * DH + aslot;
    const unsigned short* gsrc = gpb + ((size_t)e * DI + n0 + srow) * DH + aslot;
    const unsigned short* usrc = upb + ((size_t)e * DI + n0 + srow) * DH + aslot;
    int sdst = w * 512;

    int rq = (((lane >> 4) ^ ((lane >> 1) & 3)) << 3);

    f32x4 accG[4][2], accU[4][2];
#pragma unroll
    for (int i = 0; i < 4; ++i)
#pragma unroll
        for (int j = 0; j < 2; ++j) {
            accG[i][j] = (f32x4){0.f, 0.f, 0.f, 0.f};
            accU[i][j] = (f32x4){0.f, 0.f, 0.f, 0.f};
        }

#define STAGE_A(buf, k0) do { \
    GLDS(a0 + (k0),   &As[buf][sdst]); \
    GLDS(gsrc + (k0), &Bgs[buf][sdst]); \
    GLDS(usrc + (k0), &Bus[buf][sdst]); \
    } while (0)

#define KCOMP_A(cur, VMS) do { \
    asm volatile("s_waitcnt vmcnt(" VMS ")" ::: "memory"); \
    SBAR(); SCHED(); \
    s16x8 af[4], bgf[2], bu2[2]; \
    _Pragma("unroll") \
    for (int i = 0; i < 4; ++i) \
        af[i] = *(const s16x8*)&As[cur][(wm + 16 * i + (lane & 15)) * 32 + rq]; \
    _Pragma("unroll") \
    for (int j = 0; j < 2; ++j) { \
        bgf[j] = *(const s16x8*)&Bgs[cur][(wn + 16 * j + (lane & 15)) * 32 + rq]; \
        bu2[j] = *(const s16x8*)&Bus[cur][(wn + 16 * j + (lane & 15)) * 32 + rq]; \
    } \
    asm volatile("s_waitcnt lgkmcnt(0)" ::: "memory"); \
    SCHED(); \
    SBAR(); \
    SCHED(); \
    _Pragma("unroll") \
    for (int i = 0; i < 4; ++i) \
        _Pragma("unroll") \
        for (int j = 0; j < 2; ++j) { \
            accG[i][j] = __builtin_amdgcn_mfma_f32_16x16x32_bf16(af[i], bgf[j], accG[i][j], 0, 0, 0); \
            accU[i][j] = __builtin_amdgcn_mfma_f32_16x16x32_bf16(af[i], bu2[j], accU[i][j], 0, 0, 0); \
        } \
    } while (0)

    // prologue: 2 stages in flight
    STAGE_A(0, 0);
    STAGE_A(1, 32);
    int bs = 2, bc = 0;
    for (int ks = 0; ks < 30; ++ks) {
        STAGE_A(bs, (ks + 2) * 32);
        KCOMP_A(bc, "6");
        bs = (bs == 2) ? 0 : bs + 1;
        bc = (bc == 2) ? 0 : bc + 1;
    }
    KCOMP_A(0, "3");   // ks = 30
    KCOMP_A(1, "0");   // ks = 31
#undef STAGE_A
#undef KCOMP_A

#pragma unroll
    for (int i = 0; i < 4; ++i) {
        int rowb = pr0 + wm + 16 * i + ((lane >> 4) << 2);
#pragma unroll
        for (int j = 0; j < 2; ++j) {
            int col = n0 + wn + 16 * j + (lane & 15);
#pragma unroll
            for (int r = 0; r < 4; ++r) {
                float g = accG[i][j][r], u = accU[i][j][r];
                float val = (g / (1.f + __expf(-g))) * u;
                h[(size_t)(rowb + r) * DI + col] = (unsigned short)f2bf(val);
            }
        }
    }
}

// ---------------- grouped GEMM B: outP(bf16) = h Wd^T ----------------
// 128x128 tile, 4 waves of 64x64, TRIPLE-buffer LDS, 2-deep counted-vmcnt pipeline.
__global__ __launch_bounds__(256) void gemmB_kernel(
        const unsigned short* __restrict__ h,
        const unsigned short* __restrict__ dpb,
        const int* __restrict__ padOff, const int* __restrict__ counts,
        unsigned short* __restrict__ outP) {
    int bid = blockIdx.x;
    int nid = (bid & 7) * 72 + (bid >> 3);          // 576 = 8 XCD * 72, bijective
    int colblk = nid / 72, rowblk = nid - colblk * 72;
    int pr0 = rowblk * 128;
    int n0 = colblk * 128;
    int e = -1, base = 0;
#pragma unroll
    for (int i = 0; i < NE; ++i)
        if (pr0 >= padOff[i] && pr0 < padOff[i + 1]) { e = i; base = padOff[i]; }
    if (e < 0) return;
    int cnt = counts[e];

    __shared__ unsigned short As[3][128 * 32];
    __shared__ unsigned short Bs[3][128 * 32];      // 48 KB total

    int tid = threadIdx.x;
    int lane = tid & 63;
    int w = tid >> 6;
    int wm = (w >> 1) * 64;
    int wn = (w & 1) * 64;

    int srow = w * 32 + (lane >> 2);
    int aslot = (((lane & 3) ^ ((lane >> 3) & 3)) << 3);
    const unsigned short* a0   = h   + (size_t)(pr0 + srow) * DI + aslot;
    const unsigned short* a1   = h   + (size_t)(pr0 + srow + 16) * DI + aslot;
    const unsigned short* b0   = dpb + ((size_t)e * DH + n0 + srow) * DI + aslot;
    const unsigned short* b1   = dpb + ((size_t)e * DH + n0 + srow + 16) * DI + aslot;
    int sdst = w * 1024;

    int rq = (((lane >> 4) ^ ((lane >> 1) & 3)) << 3);

    f32x4 acc[4][4];
#pragma unroll
    for (int i = 0; i < 4; ++i)
#pragma unroll
        for (int j = 0; j < 4; ++j) acc[i][j] = (f32x4){0.f, 0.f, 0.f, 0.f};

#define STAGE_B(buf, k0) do { \
    GLDS(a0 + (k0), &As[buf][sdst]); \
    GLDS(a1 + (k0), &As[buf][sdst + 512]); \
    GLDS(b0 + (k0), &Bs[buf][sdst]); \
    GLDS(b1 + (k0), &Bs[buf][sdst + 512]); \
    } while (0)

#define KCOMP_B(cur, VMS) do { \
    asm volatile("s_waitcnt vmcnt(" VMS ")" ::: "memory"); \
    SBAR(); SCHED(); \
    s16x8 af[4], bf[4]; \
    _Pragma("unroll") \
    for (int i = 0; i < 4; ++i) \
        af[i] = *(const s16x8*)&As[cur][(wm + 16 * i + (lane & 15)) * 32 + rq]; \
    _Pragma("unroll") \
    for (int j = 0; j < 4; ++j) \
        bf[j] = *(const s16x8*)&Bs[cur][(wn + 16 * j + (lane & 15)) * 32 + rq]; \
    asm volatile("s_waitcnt lgkmcnt(0)" ::: "memory"); \
    SCHED(); \
    SBAR(); \
    SCHED(); \
    _Pragma("unroll") \
    for (int i = 0; i < 4; ++i) \
        _Pragma("unroll") \
        for (int j = 0; j < 4; ++j) \
            acc[i][j] = __builtin_amdgcn_mfma_f32_16x16x32_bf16(af[i], bf[j], acc[i][j], 0, 0, 0); \
    } while (0)

    STAGE_B(0, 0);
    STAGE_B(1, 32);
    int bs = 2, bc = 0;
    for (int ks = 0; ks < 42; ++ks) {
        STAGE_B(bs, (ks + 2) * 32);
        KCOMP_B(bc, "8");
        bs = (bs == 2) ? 0 : bs + 1;
        bc = (bc == 2) ? 0 : bc + 1;
    }
    KCOMP_B(0, "4");   // ks = 42
    KCOMP_B(1, "0");   // ks = 43
#undef STAGE_B
#undef KCOMP_B

#pragma unroll
    for (int i = 0; i < 4; ++i) {
        int rowb = pr0 + wm + 16 * i + ((lane >> 4) << 2);
#pragma unroll
        for (int r = 0; r < 4; ++r) {
            int prow = rowb + r;
            if (prow - base < cnt) {
#pragma unroll
                for (int j = 0; j < 4; ++j) {
                    int col = n0 + wn + 16 * j + (lane & 15);
                    outP[(size_t)prow * DH + col] = (unsigned short)f2bf(acc[i][j][r]);
                }
            }
        }
    }
}

// ---------------- combine: out[t] = w0*outP[s0] + w1*outP[s1] (bf16 in, fp32 out) ----------------
__global__ __launch_bounds__(256) void combine_kernel(const unsigned short* __restrict__ outP,
        const int* __restrict__ tokSlot, const float* __restrict__ tokW,
        float* __restrict__ out) {
    int t = blockIdx.x;
    int c = threadIdx.x * 4;
    int s0 = tokSlot[2 * t], s1 = tokSlot[2 * t + 1];
    float w0 = tokW[2 * t], w1 = tokW[2 * t + 1];
    ushort4 a = *(const ushort4*)(outP + (size_t)s0 * DH + c);
    ushort4 b = *(const ushort4*)(outP + (size_t)s1 * DH + c);
    float4 o;
    o.x = w0 * bf2f(a.x) + w1 * bf2f(b.x);
    o.y = w0 * bf2f(a.y) + w1 * bf2f(b.y);
    o.z = w0 * bf2f(a.z) + w1 * bf2f(b.z);
    o.w = w0 * bf2f(a.w) + w1 * bf2f(b.w);
    *(float4*)(out + (size_t)t * DH + c) = o;
}

extern "C" void kernel_launch(void* const* d_in, const int* in_sizes, int n_in,
                              void* d_out, int out_size, void* d_ws, size_t ws_size,
                              hipStream_t stream) {
    const float* x  = (const float*)d_in[0];
    const float* gw = (const float*)d_in[1];
    const float* gp = (const float*)d_in[2];
    const float* up = (const float*)d_in[3];
    const float* dp = (const float*)d_in[4];
    float* out = (float*)d_out;
    float* logits = out + (size_t)T_TOK * DH;

    char* ws = (char*)d_ws;
    int*   counts    = (int*)(ws + 0);
    int*   padOff    = (int*)(ws + 128);
    int*   tokE      = (int*)(ws + 4096);                       // 32 KB
    float* tokW      = (float*)(ws + 36864);                    // 32 KB
    int*   tokSlot   = (int*)(ws + 69632);                      // 32 KB
    int*   assignTok = (int*)(ws + 102400);                     // 36 KB
    unsigned short* xb   = (unsigned short*)(ws + 147456);      // 8.39 MB
    unsigned short* gpb  = (unsigned short*)(ws + 8536064);     // 23.07 MB
    unsigned short* upb  = (unsigned short*)(ws + 31604736);    // 23.07 MB
    unsigned short* dpb  = (unsigned short*)(ws + 54673408);    // 23.07 MB
    unsigned short* h    = (unsigned short*)(ws + 77742080);    // 25.95 MB
    unsigned short* outP = (unsigned short*)(ws + 8536064);     // 18.9 MB, overlaps gpb (dead after gemmA)

    const int NW8 = NE * DI * DH / 8;   // 1441792
    cvt3_kernel<<<2048, 256, 0, stream>>>(gp, up, dp, (uint4*)gpb, (uint4*)upb, (uint4*)dpb, NW8);

    router_kernel<<<T_TOK / 4, 256, 0, stream>>>(x, gw, logits, tokE, tokW, xb);
    histscatter_kernel<<<1, 1024, 0, stream>>>(tokE, counts, padOff, assignTok, tokSlot);

    gemmA_kernel<<<dim3((DI / 128) * (PADROWS / 128)), 512, 0, stream>>>(xb, gpb, upb, padOff, assignTok, h);
    gemmB_kernel<<<(DH / 128) * (PADROWS / 128), 256, 0, stream>>>(h, dpb, padOff, counts, outP);
    combine_kernel<<<T_TOK, 256, 0, stream>>>(outP, tokSlot, tokW, out);
}